// Round 12
// baseline (704.139 us; speedup 1.0000x reference)
//
#include <hip/hip_runtime.h>
#include <hip/hip_bf16.h>
#include <math.h>

// Problem dims
#define BB 32
#define TE 80
#define FEAT 4096
#define HH 256
#define W2V 256
#define TD 30
#define VV 32000
#define G4 1024   // 4*H

typedef unsigned short u16;
typedef unsigned int u32;
using f32x4 = __attribute__((ext_vector_type(4))) float;
using bf16x8 = __attribute__((ext_vector_type(8))) short;
using f16x2 = __attribute__((ext_vector_type(2))) _Float16;

#define SENT 0xFFFFFFFFu
#define NANF 0x7FC00000u

__device__ __forceinline__ float sigm(float x) { return 1.0f / (1.0f + expf(-x)); }
__device__ __forceinline__ u16 f2bf(float f) {
  u32 u = __float_as_uint(f);
  u32 r = (u + 0x7FFFu + ((u >> 16) & 1u)) >> 16;
  return (u16)r;
}
__device__ __forceinline__ u32 packh2(float lo, float hi) {
  f16x2 v = {(_Float16)lo, (_Float16)hi};
  return __builtin_bit_cast(u32, v);
}

#define AT_LOAD(p)     __hip_atomic_load((p), __ATOMIC_RELAXED, __HIP_MEMORY_SCOPE_AGENT)
#define AT_STORE(p, v) __hip_atomic_store((p), (v), __ATOMIC_RELAXED, __HIP_MEMORY_SCOPE_AGENT)

__device__ __forceinline__ float fdot2h(f16x2 a, f16x2 b, float c) {
#if __has_builtin(__builtin_amdgcn_fdot2)
  return __builtin_amdgcn_fdot2(a, b, c, false);
#else
  return c + (float)a[0] * (float)b[0] + (float)a[1] * (float)b[1];
#endif
}

// ===========================================================================
// prep: argmax | feat->bf16 | w_ih1->bf16 | XW2 MFMA (inline cvt, +bias) |
// H sentinels | A2P sentinels | bias+misc.   6297 blocks.
// ===========================================================================
__global__ __launch_bounds__(256) void prep_kernel(
    const float* __restrict__ feat, const float* __restrict__ w_ih1,
    const float* __restrict__ w_ih2, const float* __restrict__ caption,
    const float* __restrict__ onehot,
    const float* __restrict__ b_ih1, const float* __restrict__ b_hh1,
    const float* __restrict__ b_ih2, const float* __restrict__ b_hh2,
    u16* __restrict__ featb, u16* __restrict__ w_ih1b,
    float* __restrict__ XW2,
    float* __restrict__ bias1, float* __restrict__ bias2,
    u32* __restrict__ H1H, u32* __restrict__ H2H, u32* __restrict__ A2P,
    float* __restrict__ loss, int* __restrict__ ctrs,
    int* __restrict__ targets) {
  __shared__ __align__(16) char psm[50688];
  int blk = blockIdx.x, tid = threadIdx.x;
  if (blk < 928) {
    int k = blk;  // (s-1)*32 + b
    int s = (k >> 5) + 1, b = k & 31;
    const float* row = &onehot[((size_t)b * TD + s) * VV];
    float bv = -INFINITY;
    int bi = 0x7fffffff;
    for (int v = tid; v < VV; v += 256) {
      float x = row[v];
      if (x > bv || (x == bv && v < bi)) { bv = x; bi = v; }
    }
    float* sv = (float*)psm;
    int* si = (int*)(psm + 1024);
    sv[tid] = bv; si[tid] = bi;
    __syncthreads();
    for (int off = 128; off; off >>= 1) {
      if (tid < off) {
        float ov = sv[tid + off]; int oi = si[tid + off];
        if (ov > sv[tid] || (ov == sv[tid] && oi < si[tid])) { sv[tid] = ov; si[tid] = oi; }
      }
      __syncthreads();
    }
    if (tid == 0) targets[k] = si[0];
  } else if (blk < 3488) {
    int i0 = (blk - 928) * 1024 + tid;
#pragma unroll
    for (int ii = 0; ii < 4; ++ii) {
      int i = i0 + ii * 256;
      float4 v = *(const float4*)&feat[(size_t)i * 4];
      *(ushort4*)&featb[(size_t)i * 4] =
          make_ushort4(f2bf(v.x), f2bf(v.y), f2bf(v.z), f2bf(v.w));
    }
  } else if (blk < 4512) {
    int i0 = (blk - 3488) * 1024 + tid;
#pragma unroll
    for (int ii = 0; ii < 4; ++ii) {
      int i = i0 + ii * 256;
      float4 v = *(const float4*)&w_ih1[(size_t)i * 4];
      *(ushort4*)&w_ih1b[(size_t)i * 4] =
          make_ushort4(f2bf(v.x), f2bf(v.y), f2bf(v.z), f2bf(v.w));
    }
  } else if (blk < 4976) {
    // XW2[(t*32+b)][n] = bf16(caption[b][t][:]) . bf16(w_ih2[n][0:256]) + bias2[n]
    int k = blk - 4512, nb = k & 15, t = k >> 4;
    u16* As = (u16*)psm;                 // [32][264]
    u16* Bs = (u16*)(psm + 16896);       // [64][264]
    int nBase = nb * 64;
#pragma unroll
    for (int it = 0; it < 4; ++it) {
      int i = it * 256 + tid;
      int r = i >> 5, c8 = i & 31;
      const float* src = &caption[((size_t)r * TD + t) * 256 + c8 * 8];
      float4 v0 = *(const float4*)src;
      float4 v1 = *(const float4*)(src + 4);
      u16* dst = &As[r * 264 + c8 * 8];
      *(ushort4*)dst = make_ushort4(f2bf(v0.x), f2bf(v0.y), f2bf(v0.z), f2bf(v0.w));
      *(ushort4*)(dst + 4) = make_ushort4(f2bf(v1.x), f2bf(v1.y), f2bf(v1.z), f2bf(v1.w));
    }
#pragma unroll
    for (int it = 0; it < 8; ++it) {
      int i = it * 256 + tid;
      int r = i >> 5, c8 = i & 31;
      const float* src = &w_ih2[(size_t)(nBase + r) * 512 + c8 * 8];
      float4 v0 = *(const float4*)src;
      float4 v1 = *(const float4*)(src + 4);
      u16* dst = &Bs[r * 264 + c8 * 8];
      *(ushort4*)dst = make_ushort4(f2bf(v0.x), f2bf(v0.y), f2bf(v0.z), f2bf(v0.w));
      *(ushort4*)(dst + 4) = make_ushort4(f2bf(v1.x), f2bf(v1.y), f2bf(v1.z), f2bf(v1.w));
    }
    __syncthreads();
    int lane = tid & 63, w = tid >> 6;
    int lrow = lane & 15, lk = (lane >> 4) * 8;
    f32x4 acc[2];
    acc[0] = (f32x4){0.f, 0.f, 0.f, 0.f};
    acc[1] = (f32x4){0.f, 0.f, 0.f, 0.f};
#pragma unroll
    for (int ks = 0; ks < 8; ++ks) {
      bf16x8 bfr = *(const bf16x8*)&Bs[(w * 16 + lrow) * 264 + ks * 32 + lk];
#pragma unroll
      for (int m = 0; m < 2; ++m) {
        bf16x8 af = *(const bf16x8*)&As[(m * 16 + lrow) * 264 + ks * 32 + lk];
        acc[m] = __builtin_amdgcn_mfma_f32_16x16x32_bf16(af, bfr, acc[m], 0, 0, 0);
      }
    }
    int col = nBase + w * 16 + (lane & 15);
    float bv = b_ih2[col] + b_hh2[col];
    int orow = (lane >> 4) * 4;
#pragma unroll
    for (int m = 0; m < 2; ++m)
#pragma unroll
      for (int qq = 0; qq < 4; ++qq) {
        int bb = m * 16 + orow + qq;
        XW2[((size_t)t * 32 + bb) * G4 + col] = acc[m][qq] + bv;
      }
  } else if (blk < 5416) {
    int i = (blk - 4976) * 256 + tid;  // uint4 index < 112640
    uint4 z = {0u, 0u, 0u, 0u};
    uint4 s = {SENT, SENT, SENT, SENT};
    uint4 v = (i < 1024) ? z : s;      // slot T=0 = packed f16 zeros
    ((uint4*)H1H)[i] = v;
    ((uint4*)H2H)[i] = v;
  } else if (blk < 6296) {
    int i0 = (blk - 5416) * 1024 + tid;  // uint4 index < 901120
    uint4 s = {NANF, NANF, NANF, NANF};
#pragma unroll
    for (int ii = 0; ii < 4; ++ii) ((uint4*)A2P)[i0 + ii * 256] = s;
  } else {
    for (int i = tid; i < 1024; i += 256) {
      bias1[i] = b_ih1[i] + b_hh1[i];
      bias2[i] = b_ih2[i] + b_hh2[i];
    }
    if (tid == 0) { *loss = 0.0f; ctrs[0] = 0; ctrs[32] = 0; }
  }
}

// ===========================================================================
// Persistent recurrent kernel. 256 blocks x 512 threads (cooperative).
// L1 [0,128): prologue = own X1 slice (80x256 gate-col set) via MFMA -> LDS;
//   then h1 chain (wA) + a2p = w_ih2r.h1[T] (wB) publish. 128 weight regs.
// L2B [128,256): h2 chain: wC only (64 regs, no spill). Encoder saves
//   g2[t] = wC.enc_h2[t] (f16, LDS); decoder uses wC.ctx = sum sc[t]*g2[t]
//   (linearity) -> no decoder weight dot. encL stored f16x2.
// Self-validating sentinel exchange: one LLC round trip per chain step.
// ===========================================================================
struct RP {
  const float *XW2, *bias1, *bias2;
  const u16 *featb, *w_ih1b;
  const float *w_hh1, *w_ih2, *w_hh2;
  u32* H1H;     // [110][32][128] packed f16x2 of h1[T]
  u32* H2H;     // [110][32][128] packed f16x2 of h2[U]
  u32* A2P;     // [110][32][1024] f32 bits
  u16* H2NB;    // [29][32][256] bf16 decoder h2n
};

__global__ __launch_bounds__(512, 1) void recurrent_kernel(RP p) {
  __shared__ __align__(16) char smem[133120];
  int bid = blockIdx.x, tid = threadIdx.x;
  bool isL1 = bid < 128;
  int lb = isL1 ? bid : bid - 128;
  int b = lb >> 2, q = lb & 3;
  int r2 = tid >> 1, half = tid & 1;
  int g = r2 >> 6, jj = r2 & 63;
  int grow = (g << 8) + (q << 6) + jj;

  if (isL1) {
    u16* As = (u16*)smem;                    // [80][72]
    u16* Bs = (u16*)(smem + 11520);          // [256][72]
    float* X1L = (float*)(smem + 48384);     // [80][257]
    f16x2* hS = (f16x2*)(smem + 130624);     // [128]
    float* gb = (float*)(smem + 131136);     // [256]
    float* hnew = (float*)(smem + 132160);   // [64]
    // ---------------- prologue: X1 slice via MFMA ----------------
    {
      int lane = tid & 63, w = tid >> 6;
      int lrow = lane & 15, lk = (lane >> 4) * 8;
      f32x4 acc[5][2];
#pragma unroll
      for (int m = 0; m < 5; ++m)
#pragma unroll
        for (int n = 0; n < 2; ++n) acc[m][n] = (f32x4){0.f, 0.f, 0.f, 0.f};
      for (int k0 = 0; k0 < FEAT; k0 += 64) {
        for (int f = tid; f < 640; f += 512) {
          int r = f >> 3, c8 = f & 7;
          *(uint4*)&As[r * 72 + c8 * 8] =
              *(const uint4*)&p.featb[((size_t)(b * 80 + r)) * FEAT + k0 + c8 * 8];
        }
#pragma unroll
        for (int it = 0; it < 4; ++it) {
          int f = it * 512 + tid;
          int r = f >> 3, c8 = f & 7;
          int gg = r >> 6, u = r & 63;
          *(uint4*)&Bs[r * 72 + c8 * 8] =
              *(const uint4*)&p.w_ih1b[((size_t)(gg * 256 + q * 64 + u)) * FEAT + k0 + c8 * 8];
        }
        __syncthreads();
#pragma unroll
        for (int ks = 0; ks < 2; ++ks) {
          bf16x8 bfr[2];
#pragma unroll
          for (int n = 0; n < 2; ++n)
            bfr[n] = *(const bf16x8*)&Bs[((w * 2 + n) * 16 + lrow) * 72 + ks * 32 + lk];
#pragma unroll
          for (int m = 0; m < 5; ++m) {
            bf16x8 af = *(const bf16x8*)&As[(m * 16 + lrow) * 72 + ks * 32 + lk];
#pragma unroll
            for (int n = 0; n < 2; ++n)
              acc[m][n] = __builtin_amdgcn_mfma_f32_16x16x32_bf16(af, bfr[n], acc[m][n], 0, 0, 0);
          }
        }
        __syncthreads();
      }
      int lcol = lane & 15, orow = (lane >> 4) * 4;
#pragma unroll
      for (int m = 0; m < 5; ++m)
#pragma unroll
        for (int n = 0; n < 2; ++n) {
          int cn = (w * 2 + n) * 16 + lcol;
          int gc = (cn >> 6) * 256 + q * 64 + (cn & 63);
          float bv = p.bias1[gc];
#pragma unroll
          for (int qq = 0; qq < 4; ++qq)
            X1L[(m * 16 + orow + qq) * 257 + cn] = acc[m][n][qq] + bv;
        }
      __syncthreads();
    }
    // ---------------- chain ----------------
    f16x2 wA[64], wB[64];
    {
      const float4* sA = (const float4*)(p.w_hh1 + (size_t)grow * 256 + half * 128);
      const float4* sB = (const float4*)(p.w_ih2 + (size_t)grow * 512 + 256 + half * 128);
#pragma unroll
      for (int k = 0; k < 32; ++k) {
        float4 v = sA[k];
        wA[k * 2 + 0] = f16x2{(_Float16)v.x, (_Float16)v.y};
        wA[k * 2 + 1] = f16x2{(_Float16)v.z, (_Float16)v.w};
        float4 u = sB[k];
        wB[k * 2 + 0] = f16x2{(_Float16)u.x, (_Float16)u.y};
        wB[k * 2 + 1] = f16x2{(_Float16)u.z, (_Float16)u.w};
      }
    }
    float c1 = 0.f;
    float b1v0 = 0, b1v1 = 0, b1v2 = 0, b1v3 = 0;
    if (tid < 64) {
      b1v0 = p.bias1[(q << 6) + tid];
      b1v1 = p.bias1[256 + (q << 6) + tid];
      b1v2 = p.bias1[512 + (q << 6) + tid];
      b1v3 = p.bias1[768 + (q << 6) + tid];
    }
    for (int T = 0; T <= 109; ++T) {
      float x0 = b1v0, x1 = b1v1, x2 = b1v2, x3 = b1v3;
      if (tid < 64 && T < TE) {
        x0 = X1L[T * 257 + tid];
        x1 = X1L[T * 257 + 64 + tid];
        x2 = X1L[T * 257 + 128 + tid];
        x3 = X1L[T * 257 + 192 + tid];
      }
      if (tid < 128) {
        const u32* src = &p.H1H[((size_t)T * 32 + b) * 128 + tid];
        u32 v = AT_LOAD(src);
        int gd = 0;
        while (v == SENT && ++gd < (1 << 24)) {
          __builtin_amdgcn_s_sleep(1);
          v = AT_LOAD(src);
        }
        hS[tid] = __builtin_bit_cast(f16x2, v);
      }
      __syncthreads();  // S1
      float a1 = 0.f, a2 = 0.f;
      {
        const uint4* hv = ((const uint4*)hS) + half * 16;
#pragma unroll
        for (int k = 0; k < 16; ++k) {
          uint4 uu = hv[k];
          f16x2 e0 = __builtin_bit_cast(f16x2, uu.x), e1 = __builtin_bit_cast(f16x2, uu.y);
          f16x2 e2 = __builtin_bit_cast(f16x2, uu.z), e3 = __builtin_bit_cast(f16x2, uu.w);
          a1 = fdot2h(e0, wA[k * 4 + 0], a1);
          a2 = fdot2h(e0, wB[k * 4 + 0], a2);
          a1 = fdot2h(e1, wA[k * 4 + 1], a1);
          a2 = fdot2h(e1, wB[k * 4 + 1], a2);
          a1 = fdot2h(e2, wA[k * 4 + 2], a1);
          a2 = fdot2h(e2, wB[k * 4 + 2], a2);
          a1 = fdot2h(e3, wA[k * 4 + 3], a1);
          a2 = fdot2h(e3, wB[k * 4 + 3], a2);
        }
      }
      a1 += __shfl_xor(a1, 1);
      a2 += __shfl_xor(a2, 1);
      if (half == 0) {
        gb[r2] = a1;
        if (T >= 1)
          AT_STORE(&p.A2P[((size_t)T * 32 + b) * 1024 + grow], __float_as_uint(a2));
      }
      __syncthreads();  // S2
      if (T <= 108) {
        if (tid < 64) {
          float gi = gb[tid] + x0;
          float gf = gb[64 + tid] + x1;
          float gG = gb[128 + tid] + x2;
          float go = gb[192 + tid] + x3;
          c1 = sigm(gf) * c1 + sigm(gi) * tanhf(gG);
          hnew[tid] = sigm(go) * tanhf(c1);
        }
        if (tid < 32) {  // same wave as hnew writers -> ordered
          u32 pk = packh2(hnew[2 * tid], hnew[2 * tid + 1]);
          AT_STORE(&p.H1H[((size_t)(T + 1) * 32 + b) * 128 + (q << 5) + tid], pk);
        }
      }
    }
  } else {
    f16x2* encLh = (f16x2*)smem;             // [80][132] f16x2
    u16* g2Lh = (u16*)(smem + 42240);        // [80][264] u16
    f16x2* hS = (f16x2*)(smem + 84480);      // [128]
    float* a2pS = (float*)(smem + 85536);    // [256]
    float* gb = (float*)(smem + 86560);      // [256]
    float* hnew = (float*)(smem + 87584);    // [64]
    float* ps = (float*)(smem + 87840);      // [320]
    float* sc = (float*)(smem + 89120);      // [80]
    float* red = (float*)(smem + 89440);     // [4]
    f16x2 wC[64];
    {
      const float4* sC = (const float4*)(p.w_hh2 + (size_t)grow * 256 + half * 128);
#pragma unroll
      for (int k = 0; k < 32; ++k) {
        float4 u = sC[k];
        wC[k * 2 + 0] = f16x2{(_Float16)u.x, (_Float16)u.y};
        wC[k * 2 + 1] = f16x2{(_Float16)u.z, (_Float16)u.w};
      }
    }
    float c2 = 0.f;
    float b2v0 = 0, b2v1 = 0, b2v2 = 0, b2v3 = 0;
    if (tid < 64) {
      b2v0 = p.bias2[(q << 6) + tid];
      b2v1 = p.bias2[256 + (q << 6) + tid];
      b2v2 = p.bias2[512 + (q << 6) + tid];
      b2v3 = p.bias2[768 + (q << 6) + tid];
    }
    for (int U = 1; U <= 109; ++U) {
      float x0 = b2v0, x1 = b2v1, x2 = b2v2, x3 = b2v3;
      if (tid < 64 && U >= 81) {
        const float* xb = &p.XW2[((size_t)(U - 81) * 32 + b) * G4 + (q << 6) + tid];
        x0 = xb[0]; x1 = xb[256]; x2 = xb[512]; x3 = xb[768];  // bias already in XW2
      }
      // concurrent polls: h2[U-1] (pure spin) and a2p[U]
      if (tid < 128) {
        const u32* src = &p.H2H[((size_t)(U - 1) * 32 + b) * 128 + tid];
        u32 v = AT_LOAD(src);
        int gd = 0;
        while (v == SENT && ++gd < (1 << 26)) v = AT_LOAD(src);
        f16x2 hp = __builtin_bit_cast(f16x2, v);
        hS[tid] = hp;
        if (U >= 2 && U <= 81) encLh[(U - 2) * 132 + tid] = hp;
      } else if (tid < 384) {
        int rr = tid - 128;
        int growp = ((rr >> 6) << 8) + (q << 6) + (rr & 63);
        const u32* src = &p.A2P[((size_t)U * 32 + b) * 1024 + growp];
        u32 v = AT_LOAD(src);
        int gd = 0;
        while (v == NANF && ++gd < (1 << 24)) {
          __builtin_amdgcn_s_sleep(1);
          v = AT_LOAD(src);
        }
        a2pS[rr] = __uint_as_float(v);
      }
      __syncthreads();  // S1
      float a2p0 = 0, a2p1 = 0, a2p2 = 0, a2p3 = 0;
      if (tid < 64) {
        a2p0 = a2pS[tid]; a2p1 = a2pS[64 + tid];
        a2p2 = a2pS[128 + tid]; a2p3 = a2pS[192 + tid];
      }
      if (U <= 81) {
        // encoder-style: a2 = wC . h2[U-1], save g2
        float a2 = 0.f;
        const uint4* hv = ((const uint4*)hS) + half * 16;
#pragma unroll
        for (int k = 0; k < 16; ++k) {
          uint4 uu = hv[k];
          a2 = fdot2h(__builtin_bit_cast(f16x2, uu.x), wC[k * 4 + 0], a2);
          a2 = fdot2h(__builtin_bit_cast(f16x2, uu.y), wC[k * 4 + 1], a2);
          a2 = fdot2h(__builtin_bit_cast(f16x2, uu.z), wC[k * 4 + 2], a2);
          a2 = fdot2h(__builtin_bit_cast(f16x2, uu.w), wC[k * 4 + 3], a2);
        }
        a2 += __shfl_xor(a2, 1);
        if (half == 0) {
          gb[r2] = a2;
          if (U >= 2) g2Lh[(U - 2) * 264 + r2] = __builtin_bit_cast(u16, (_Float16)a2);
        }
        __syncthreads();  // S2
      } else {
        // decoder: scores (f16 dot, stride-4 interleave) -> softmax -> combine g2
        if (tid < 320) {
          int t = tid >> 2, kq = tid & 3;
          float a = 0.f;
          const f16x2* e = &encLh[t * 132];
#pragma unroll
          for (int i = 0; i < 32; ++i)
            a = fdot2h(e[kq + 4 * i], hS[kq + 4 * i], a);
          ps[tid] = a;
        }
        __syncthreads();  // S2
        float sco = 0.f;
        if (tid < TE) sco = ps[4 * tid] + ps[4 * tid + 1] + ps[4 * tid + 2] + ps[4 * tid + 3];
        float av = (tid < TE) ? sco : -INFINITY;
#pragma unroll
        for (int d = 32; d; d >>= 1) av = fmaxf(av, __shfl_xor(av, d));
        if (tid == 0) red[0] = av;
        if (tid == 64) red[1] = av;
        __syncthreads();  // S3
        float m = fmaxf(red[0], red[1]);
        float e2 = (tid < TE) ? expf(sco - m) : 0.f;
        float sv = e2;
#pragma unroll
        for (int d = 32; d; d >>= 1) sv += __shfl_xor(sv, d);
        if (tid == 0) red[2] = sv;
        if (tid == 64) red[3] = sv;
        __syncthreads();  // S4
        float inv = 1.0f / (red[2] + red[3]);
        if (tid < TE) sc[tid] = e2 * inv;
        __syncthreads();  // S5
        // wC.ctx = sum_t sc[t] * g2[t]; t parity split by half
        float acc = 0.f;
#pragma unroll 8
        for (int k = 0; k < 40; ++k) {
          int t = 2 * k + half;
          float g2v = (float)__builtin_bit_cast(_Float16, g2Lh[t * 264 + r2]);
          acc = fmaf(sc[t], g2v, acc);
        }
        acc += __shfl_xor(acc, 1);
        if (half == 0) gb[r2] = acc;
        __syncthreads();  // S6
      }
      if (tid < 64) {
        float gi = gb[tid] + a2p0 + x0;
        float gf = gb[64 + tid] + a2p1 + x1;
        float gG = gb[128 + tid] + a2p2 + x2;
        float go = gb[192 + tid] + a2p3 + x3;
        c2 = sigm(gf) * c2 + sigm(gi) * tanhf(gG);
        float h = sigm(go) * tanhf(c2);
        hnew[tid] = h;
        if (U >= 81)
          p.H2NB[((size_t)(U - 81) * 32 + b) * 256 + (q << 6) + tid] = f2bf(h);
      }
      if (tid < 32) {  // same wave as hnew writers
        u32 pk = packh2(hnew[2 * tid], hnew[2 * tid + 1]);
        AT_STORE(&p.H2H[((size_t)U * 32 + b) * 128 + (q << 5) + tid], pk);
      }
    }
  }
}

// ===========================================================================
// Fused logits + CE partials + final reduce (250 co-resident blocks).
// ===========================================================================
__global__ __launch_bounds__(256, 1) void logits_final_kernel(
    const u16* __restrict__ H2NB, const float* __restrict__ w_out,
    const float* __restrict__ b_out, const int* __restrict__ targets,
    u32* __restrict__ pmaxA, u32* __restrict__ psumA, u32* __restrict__ tgtv,
    float* __restrict__ loss, int* __restrict__ ctrs, float* __restrict__ out) {
  __shared__ __align__(16) u16 bS[32768];
  __shared__ __align__(16) u16 aS[32 * 264];
  __shared__ int tS[32];
  __shared__ float sm[256];
  int tid = threadIdx.x, bid = blockIdx.x;
#pragma unroll
  for (int it = 0; it < 16; ++it) {
    int id = it * 256 + tid;
    int nt = id >> 9, rr = (id >> 5) & 15, kg = id & 31;
    int n = bid * 128 + nt * 16 + rr;
    const float* src = &w_out[(size_t)n * 256 + kg * 8];
    float4 v0 = *(const float4*)src;
    float4 v1 = *(const float4*)(src + 4);
    u16* dst = &bS[(size_t)((nt * 32 + kg) * 16 + rr) * 8];
    *(ushort4*)dst = make_ushort4(f2bf(v0.x), f2bf(v0.y), f2bf(v0.z), f2bf(v0.w));
    *(ushort4*)(dst + 4) = make_ushort4(f2bf(v1.x), f2bf(v1.y), f2bf(v1.z), f2bf(v1.w));
  }
  int wid = tid >> 6, lane = tid & 63, lcol = lane & 15, lk = lane >> 4;
  float bo[2];
#pragma unroll
  for (int n = 0; n < 2; ++n) bo[n] = b_out[(bid * 8 + wid * 2 + n) * 16 + lcol];

  for (int rg = 0; rg < 29; ++rg) {
    __syncthreads();
    for (int i = tid; i < 1024; i += 256) {
      int r = i >> 5, c8 = i & 31;
      *(uint4*)&aS[r * 264 + c8 * 8] =
          *(const uint4*)&H2NB[(size_t)rg * 8192 + r * 256 + c8 * 8];
    }
    if (tid < 32) tS[tid] = targets[rg * 32 + tid];
    __syncthreads();
    f32x4 acc[2][2];
#pragma unroll
    for (int m = 0; m < 2; ++m)
#pragma unroll
      for (int n = 0; n < 2; ++n) acc[m][n] = (f32x4){0.f, 0.f, 0.f, 0.f};
#pragma unroll
    for (int ks = 0; ks < 8; ++ks) {
      bf16x8 a0 = *(const bf16x8*)&aS[lcol * 264 + ks * 32 + lk * 8];
      bf16x8 a1 = *(const bf16x8*)&aS[(16 + lcol) * 264 + ks * 32 + lk * 8];
      bf16x8 b0 = *(const bf16x8*)&bS[(wid * 2) * 4096 + ((ks * 4 + lk) * 16 + lcol) * 8];
      bf16x8 b1 = *(const bf16x8*)&bS[(wid * 2 + 1) * 4096 + ((ks * 4 + lk) * 16 + lcol) * 8];
      acc[0][0] = __builtin_amdgcn_mfma_f32_16x16x32_bf16(a0, b0, acc[0][0], 0, 0, 0);
      acc[0][1] = __builtin_amdgcn_mfma_f32_16x16x32_bf16(a0, b1, acc[0][1], 0, 0, 0);
      acc[1][0] = __builtin_amdgcn_mfma_f32_16x16x32_bf16(a1, b0, acc[1][0], 0, 0, 0);
      acc[1][1] = __builtin_amdgcn_mfma_f32_16x16x32_bf16(a1, b1, acc[1][1], 0, 0, 0);
    }
    int nbase = (bid * 8 + wid * 2) * 16 + lcol;
#pragma unroll
    for (int m = 0; m < 2; ++m) {
      float pm[4], psv[4];
#pragma unroll
      for (int qq = 0; qq < 4; ++qq) {
        float v0 = acc[m][0][qq] + bo[0];
        float v1 = acc[m][1][qq] + bo[1];
        int r = m * 16 + lk * 4 + qq;
        int tg = tS[r];
        if (tg == nbase) AT_STORE(&tgtv[rg * 32 + r], __float_as_uint(v0));
        if (tg == nbase + 16) AT_STORE(&tgtv[rg * 32 + r], __float_as_uint(v1));
        float mx = fmaxf(v0, v1);
#pragma unroll
        for (int d = 1; d < 16; d <<= 1) mx = fmaxf(mx, __shfl_xor(mx, d));
        float e = expf(v0 - mx) + expf(v1 - mx);
#pragma unroll
        for (int d = 1; d < 16; d <<= 1) e += __shfl_xor(e, d);
        pm[qq] = mx;
        psv[qq] = e;
      }
      if (lcol == 0) {
        int chunk = bid * 4 + wid;
#pragma unroll
        for (int qq = 0; qq < 4; ++qq) {
          int r2 = rg * 32 + m * 16 + lk * 4 + qq;
          AT_STORE(&pmaxA[(size_t)r2 * 1000 + chunk], __float_as_uint(pm[qq]));
          AT_STORE(&psumA[(size_t)r2 * 1000 + chunk], __float_as_uint(psv[qq]));
        }
      }
    }
  }
  asm volatile("s_waitcnt vmcnt(0)" ::: "memory");
  __syncthreads();
  if (tid == 0) {
    __hip_atomic_fetch_add(&ctrs[0], 1, __ATOMIC_RELEASE, __HIP_MEMORY_SCOPE_AGENT);
    int gd = 0;
    while (__hip_atomic_load(&ctrs[0], __ATOMIC_ACQUIRE, __HIP_MEMORY_SCOPE_AGENT) < 250 &&
           ++gd < (1 << 26))
      __builtin_amdgcn_s_sleep(2);
  }
  __syncthreads();
#pragma unroll
  for (int k = 0; k < 4; ++k) {
    int row = bid * 4 + k;
    if (row < 928) {
      const u32* pm = pmaxA + (size_t)row * 1000;
      const u32* psv = psumA + (size_t)row * 1000;
      float m = -INFINITY;
      for (int c = tid; c < 1000; c += 256) m = fmaxf(m, __uint_as_float(AT_LOAD(&pm[c])));
      sm[tid] = m;
      __syncthreads();
      for (int off = 128; off; off >>= 1) {
        if (tid < off) sm[tid] = fmaxf(sm[tid], sm[tid + off]);
        __syncthreads();
      }
      float M = sm[0];
      __syncthreads();
      float s = 0.f;
      for (int c = tid; c < 1000; c += 256)
        s += __uint_as_float(AT_LOAD(&psv[c])) * expf(__uint_as_float(AT_LOAD(&pm[c])) - M);
      sm[tid] = s;
      __syncthreads();
      for (int off = 128; off; off >>= 1) {
        if (tid < off) sm[tid] += sm[tid + off];
        __syncthreads();
      }
      if (tid == 0) {
        float tv = __uint_as_float(AT_LOAD(&tgtv[row]));
        atomicAdd(loss, (M + logf(sm[0]) - tv) * (1.0f / 1024.0f));
      }
      __syncthreads();
    }
  }
  asm volatile("s_waitcnt vmcnt(0)" ::: "memory");
  if (tid == 0) {
    int old = __hip_atomic_fetch_add(&ctrs[32], 1, __ATOMIC_ACQ_REL, __HIP_MEMORY_SCOPE_AGENT);
    if (old == 249) out[0] = __uint_as_float(AT_LOAD((u32*)loss));
  }
}

// ---------------------------------------------------------------------------
extern "C" void kernel_launch(void* const* d_in, const int* in_sizes, int n_in,
                              void* d_out, int out_size, void* d_ws, size_t ws_size,
                              hipStream_t stream) {
  (void)in_sizes; (void)n_in; (void)out_size; (void)ws_size;
  const float* feat    = (const float*)d_in[0];
  const float* caption = (const float*)d_in[1];
  const float* onehot  = (const float*)d_in[2];
  const float* w_ih1   = (const float*)d_in[4];
  const float* w_hh1   = (const float*)d_in[5];
  const float* b_ih1   = (const float*)d_in[6];
  const float* b_hh1   = (const float*)d_in[7];
  const float* w_ih2   = (const float*)d_in[8];
  const float* w_hh2   = (const float*)d_in[9];
  const float* b_ih2   = (const float*)d_in[10];
  const float* b_hh2   = (const float*)d_in[11];
  const float* w_out   = (const float*)d_in[12];
  const float* b_out   = (const float*)d_in[13];

  char* p = (char*)d_ws;
  auto alloc = [&](size_t bytes) {
    char* r = p;
    p += (bytes + 255) & ~(size_t)255;
    return r;
  };
  float* XW2     = (float*)alloc(29ull * 32 * 1024 * 4);   // 3.8 MB
  float* bias1   = (float*)alloc(1024 * 4);
  float* bias2   = (float*)alloc(1024 * 4);
  u32*   H1H     = (u32*)alloc(110ull * 32 * 128 * 4);     // 1.8 MB
  u32*   H2H     = (u32*)alloc(110ull * 32 * 128 * 4);     // 1.8 MB
  u32*   A2P     = (u32*)alloc(110ull * 32 * 1024 * 4);    // 14.4 MB
  u16*   H2NB    = (u16*)alloc(29ull * 8192 * 2);
  u32*   pmaxA   = (u32*)alloc(928ull * 1000 * 4);
  u32*   psumA   = (u32*)alloc(928ull * 1000 * 4);
  u32*   tgtv    = (u32*)alloc(928 * 4);
  float* lossacc = (float*)alloc(256);
  int*   ctrs    = (int*)alloc(256);
  int*   targets = (int*)alloc(29 * 32 * 4);
  u16*   featb   = (u16*)alloc(2560ull * 4096 * 2);        // 21 MB
  u16*   w_ih1b  = (u16*)alloc(1024ull * 4096 * 2);        // 8.4 MB

  prep_kernel<<<6297, 256, 0, stream>>>(
      feat, w_ih1, w_ih2, caption, onehot,
      b_ih1, b_hh1, b_ih2, b_hh2,
      featb, w_ih1b, XW2,
      bias1, bias2, H1H, H2H, A2P, lossacc, ctrs, targets);

  RP rp;
  rp.XW2 = XW2; rp.bias1 = bias1; rp.bias2 = bias2;
  rp.featb = featb; rp.w_ih1b = w_ih1b;
  rp.w_hh1 = w_hh1; rp.w_ih2 = w_ih2; rp.w_hh2 = w_hh2;
  rp.H1H = H1H; rp.H2H = H2H; rp.A2P = A2P; rp.H2NB = H2NB;
  void* args[] = {&rp};
  hipLaunchCooperativeKernel((const void*)recurrent_kernel, dim3(256), dim3(512),
                             args, 0, stream);

  logits_final_kernel<<<250, 256, 0, stream>>>(H2NB, w_out, b_out, targets,
                                               pmaxA, psumA, tgtv, lossacc, ctrs,
                                               (float*)d_out);
}